// Round 21
// baseline (4035.363 us; speedup 1.0000x reference)
//
#include <hip/hip_runtime.h>
#include <cstddef>

// LSTM: x[64,512,512] f32, kernel[512,4096] f32, rec_kernel[1024,4096] f32,
// bias[4096] f32 -> h_last[64,1024] f32.
// R12: x-part moved into the h-load shadow, on the R11 (best, 1657us) base.
// Evidence: R11's coalesced h loads won -23% (2157->1657), confirming the
// request-path theory. At 1 block/CU there is 1 wave/SIMD: ZERO TLP, so the
// post-poll h-load RT (~900cy) is fully serial. R11 ran the h-independent
// x-part BEFORE the poll where it hides nothing (poll-pass time is set by
// the last producer). This round's ONLY change: after poll/relay, issue the
// 8 coalesced h-loads FIRST, run the x-part (loads+MFMAs) inside the load
// flight, then vmcnt(0)+sched_barrier(0)+h-MFMAs. Everything else is
// byte-identical to R11 (R7 sync: per-wave fetch_add counters, wave0 poll +
// LDS go_flag relay, 1 barrier/step, double-buffered [kc][mt][r][kdim] slab).

namespace {
constexpr int cB = 64;
constexpr int cT = 512;
constexpr int cD = 512;
constexpr int cU = 1024;
constexpr int cG = 4096;   // 4*U
constexpr int NBLK = 256;
constexpr int NT = 256;
}

typedef __attribute__((ext_vector_type(8))) short   short8;
typedef __attribute__((ext_vector_type(8))) __bf16  bf16x8;
typedef __attribute__((ext_vector_type(4))) float   f32x4;

__device__ inline short f2bf(float f) {
  unsigned u = __float_as_uint(f);
  u += 0x7fffu + ((u >> 16) & 1u);   // round-to-nearest-even
  return (short)(u >> 16);
}

__device__ inline f32x4 mfma16(short8 a, short8 b, f32x4 c) {
  return __builtin_amdgcn_mfma_f32_16x16x32_bf16(
      __builtin_bit_cast(bf16x8, a), __builtin_bit_cast(bf16x8, b), c, 0, 0, 0);
}

__device__ inline float sigm(float x) { return 1.0f / (1.0f + __expf(-x)); }
__device__ inline float tanh_(float x) {
  float a = fabsf(x);
  float e = __expf(-2.0f * a);
  float t = (1.0f - e) / (1.0f + e);
  return x < 0.0f ? -t : t;
}

// 16B MALL-coherent load (bypasses L1/L2 via sc0 sc1). Caller must
// s_waitcnt vmcnt(0) + sched_barrier(0) before consuming (rule #18).
__device__ inline f32x4 ald16(const void* p) {
  f32x4 r;
  asm volatile("global_load_dwordx4 %0, %1, off sc0 sc1"
               : "=&v"(r) : "v"(p));
  return r;
}

__global__ __launch_bounds__(NT, 1) void lstm_persist(
    const float* __restrict__ x, const float* __restrict__ wk,
    const float* __restrict__ wr, const float* __restrict__ bias,
    float* __restrict__ out, short* __restrict__ xbf,
    short* hx, unsigned* cnt, unsigned* flags) {
  const int tid  = threadIdx.x;
  const int wv   = tid >> 6;        // wave = K-slice owner (kc === wv mod 4)
  const int lane = tid & 63;
  const int n    = lane & 15;       // MFMA A row m / C col
  const int quad = lane >> 4;
  const int bid  = blockIdx.x;
  const int mt   = bid & 3;         // batch m-tile (16 rows each)
  const int cg   = bid >> 2;        // u-group 0..63 (16 u each)
  const int ub   = cg * 16;

  __shared__ float zsh[4 * 16 * 66]; // [wave][row][gate*16+u], pad 66
  __shared__ unsigned go_flag;       // LDS epoch relay (monotonic)

  if (tid == 0) go_flag = 0u;

  // ---- phase 0: convert x to bf16 once (grid-stride) ----
  {
    const f32x4* xv = reinterpret_cast<const f32x4*>(x);
    short8* xo = reinterpret_cast<short8*>(xbf);
    const size_t nvec = (size_t)cB * cT * cD / 8;
    for (size_t i = (size_t)bid * NT + tid; i < nvec; i += (size_t)NBLK * NT) {
      f32x4 v0 = xv[2 * i];
      f32x4 v1 = xv[2 * i + 1];
      short8 s;
      s[0] = f2bf(v0[0]); s[1] = f2bf(v0[1]); s[2] = f2bf(v0[2]); s[3] = f2bf(v0[3]);
      s[4] = f2bf(v1[0]); s[5] = f2bf(v1[1]); s[6] = f2bf(v1[2]); s[7] = f2bf(v1[3]);
      xo[i] = s;
    }
  }

  // ---- time-invariant W fragments: Bf[i][g], kc = wv + 4*i, i=0..11 ----
  // B[k][n]: n = lane&15 col-in-tile, k = quad*8 + j. Gate g col = g*cU+ub+n.
  short8 Bf[12][4];
  #pragma unroll
  for (int i = 0; i < 12; ++i) {
    const int kc = wv + 4 * i;
    const int k0 = kc * 32 + quad * 8;
    #pragma unroll
    for (int g = 0; g < 4; ++g) {
      const int col = g * cU + ub + n;
      short8 b;
      #pragma unroll
      for (int j = 0; j < 8; ++j) {
        const int k = k0 + j;
        const float wgt = (k < cD) ? wk[(size_t)k * cG + col]
                                   : wr[(size_t)(k - cD) * cG + col];
        b[j] = f2bf(wgt);
      }
      Bf[i][g] = b;
    }
  }

  // ---- distributed epilogue mapping: thread -> (row, single u) ----
  const int erow = tid >> 4;        // 0..15
  const int eu   = tid & 15;        // 0..15
  const int hrow = mt * 16 + erow;  // global batch row this thread owns
  const float bi  = bias[0 * cU + ub + eu];
  const float bff = bias[1 * cU + ub + eu];
  const float bc  = bias[2 * cU + ub + eu];
  const float bo  = bias[3 * cU + ub + eu];
  float cst = 0.0f;

  // A-frag addressing for x: A[m][k], m = lane&15 -> batch row, k = quad*8+j
  const int brow = mt * 16 + n;
  const short* xrow = xbf + (size_t)brow * cT * cD + quad * 8;

  // ---- initial full-grid barrier: xbf ready everywhere ----
  __builtin_amdgcn_fence(__ATOMIC_RELEASE, "agent");
  __syncthreads();
  if (tid == 0)
    __hip_atomic_store(flags + bid * 16, 1u, __ATOMIC_RELEASE,
                       __HIP_MEMORY_SCOPE_AGENT);
  if (wv == 0) {
    #pragma unroll
    for (int j = 0; j < 4; ++j) {
      const unsigned* fp = flags + (j * 64 + lane) * 16;
      while (__hip_atomic_load(fp, __ATOMIC_RELAXED,
                               __HIP_MEMORY_SCOPE_AGENT) < 1u) {}
    }
  }
  __syncthreads();
  __builtin_amdgcn_fence(__ATOMIC_ACQUIRE, "agent");

  const int mygrp = mt * 4 + (cg >> 4);   // this block's producer counter
  // consumer h-load base: slab layout [kc=32][mt=4][r=16][kdim=32] bf16.
  // lane (n,quad), load i -> byte off = (wv+4i)*4096 + mt*1024 + n*64 + quad*16
  const char* hcons = reinterpret_cast<const char*>(hx) +
                      (size_t)wv * 4096 + (size_t)mt * 1024 +
                      (size_t)n * 64 + (size_t)quad * 16;
  // producer store index (shorts): h[row erow][u=ub+eu] ->
  // kc = cg>>1, kdim = (cg&1)*16 + eu
  const size_t ppub = ((size_t)(cg >> 1) * 4 + mt) * 512 +
                      (size_t)erow * 32 + (size_t)(cg & 1) * 16 + eu;

  for (int t = 0; t < cT; ++t) {
    f32x4 acc[4] = {{0,0,0,0},{0,0,0,0},{0,0,0,0},{0,0,0,0}};
    const short* xr = xrow + (size_t)t * cD;

    if (t > 0) {
      // ---- arrival wait (R7-exact): wave0 polls 4 counters, sleep(1);
      //      waves 1-3 released via LDS go_flag relay ----
      if (wv == 0) {
        if (lane < 4) {
          const unsigned* cp = cnt + (mt * 4 + lane) * 32;
          const unsigned tgt = 64u * (unsigned)t;
          while (__hip_atomic_load(cp, __ATOMIC_RELAXED,
                                   __HIP_MEMORY_SCOPE_AGENT) < tgt)
            __builtin_amdgcn_s_sleep(1);
        }
        __hip_atomic_store(&go_flag, (unsigned)t, __ATOMIC_RELEASE,
                           __HIP_MEMORY_SCOPE_WORKGROUP);
      } else {
        while (__hip_atomic_load(&go_flag, __ATOMIC_ACQUIRE,
                                 __HIP_MEMORY_SCOPE_WORKGROUP) < (unsigned)t) {}
      }
      asm volatile("" ::: "memory");   // no load hoisting above the wait

      // ---- issue coalesced h loads FIRST (RT starts ticking) ----
      const char* hb = hcons + (size_t)((t - 1) & 1) * 131072;
      f32x4 hv[8];
      #pragma unroll
      for (int i = 0; i < 8; ++i)
        hv[i] = ald16(hb + (size_t)i * 16384);

      // ---- x-part runs INSIDE the h-load flight (h-independent) ----
      #pragma unroll
      for (int i = 0; i < 4; ++i) {
        short8 af = *reinterpret_cast<const short8*>(xr + (wv + 4 * i) * 32);
        #pragma unroll
        for (int g = 0; g < 4; ++g) acc[g] = mfma16(af, Bf[i][g], acc[g]);
      }

      asm volatile("s_waitcnt vmcnt(0)" ::: "memory");
      __builtin_amdgcn_sched_barrier(0);   // rule #18: pin MFMAs after wait

      #pragma unroll
      for (int i = 0; i < 8; ++i) {
        short8 hr = __builtin_bit_cast(short8, hv[i]);
        #pragma unroll
        for (int g = 0; g < 4; ++g)
          acc[g] = mfma16(hr, Bf[4 + i][g], acc[g]);
      }
    } else {
      // t=0: x-part only
      #pragma unroll
      for (int i = 0; i < 4; ++i) {
        short8 af = *reinterpret_cast<const short8*>(xr + (wv + 4 * i) * 32);
        #pragma unroll
        for (int g = 0; g < 4; ++g) acc[g] = mfma16(af, Bf[i][g], acc[g]);
      }
    }

    // ---- per-wave partial z to zsh plane wv ----
    // C/D layout: col = n, row = quad*4 + r
    #pragma unroll
    for (int g = 0; g < 4; ++g)
      #pragma unroll
      for (int r = 0; r < 4; ++r)
        zsh[(wv * 16 + quad * 4 + r) * 66 + g * 16 + n] = acc[g][r];
    __syncthreads();   // the ONLY barrier per step

    // ---- distributed epilogue: 1 u per thread; sum 4 wave-planes ----
    float z[4];
    #pragma unroll
    for (int g = 0; g < 4; ++g)
      z[g] = zsh[(erow) * 66 + g * 16 + eu] +
             zsh[(16 + erow) * 66 + g * 16 + eu] +
             zsh[(32 + erow) * 66 + g * 16 + eu] +
             zsh[(48 + erow) * 66 + g * 16 + eu];
    const float ig = sigm(z[0] + bi);
    const float fg = sigm(z[1] + bff);
    const float gg = tanh_(z[2] + bc);
    const float og = sigm(z[3] + bo);
    cst = fg * cst + ig * gg;
    const float h = og * tanh_(cst);

    if (t == cT - 1) {
      out[(size_t)hrow * cU + ub + eu] = h;
    } else {
      // publish into [kc][mt][r][kdim] slab (2B per thread)
      __hip_atomic_store(hx + (size_t)(t & 1) * 65536 + ppub, f2bf(h),
                         __ATOMIC_RELAXED, __HIP_MEMORY_SCOPE_AGENT);
      // per-wave drain + signal (R7-exact)
      asm volatile("s_waitcnt vmcnt(0)" ::: "memory");
      if (lane == 0)
        __hip_atomic_fetch_add(cnt + mygrp * 32, 1u, __ATOMIC_RELAXED,
                               __HIP_MEMORY_SCOPE_AGENT);
    }
  }
}

extern "C" void kernel_launch(void* const* d_in, const int* in_sizes, int n_in,
                              void* d_out, int out_size, void* d_ws, size_t ws_size,
                              hipStream_t stream) {
  const float* x    = (const float*)d_in[0];
  const float* wk   = (const float*)d_in[1];
  const float* wr   = (const float*)d_in[2];
  const float* bias = (const float*)d_in[3];
  float* out = (float*)d_out;

  char* ws = (char*)d_ws;
  unsigned* flags = (unsigned*)ws;                 // 256 slots x 64B = 16 KB
  unsigned* cnt   = (unsigned*)(ws + 16384);       // 16 counters x 128B = 2 KB
  short* hx  = (short*)(ws + 18432);               // 2 x 128KB bf16 h slabs
  short* xbf = (short*)(ws + 18432 + 262144);      // x bf16, 32 MB

  // zero flags (startup barrier) + counters (monotonic arrival counts).
  hipMemsetAsync(ws, 0, 18432, stream);

  lstm_persist<<<dim3(NBLK), dim3(NT), 0, stream>>>(
      x, wk, wr, bias, out, xbf, hx, cnt, flags);
}